// Round 16
// baseline (749.455 us; speedup 1.0000x reference)
//
#include <hip/hip_runtime.h>

// ---------------------------------------------------------------------------
// Petri_GCN: 3x GCNConv(64->64) + MLP readout (64->32->1) + segment-mean pool
// All fp32 (abs threshold forbids bf16/MFMA; no fp32 MFMA on CDNA4).
// R1: CSR-by-dst + gather. R3: Ts=(X@W)*dinv; gather pure-write.
// R5: bucketed CSR build. R8-R12: gemm shape search; spill lessons.
// R13: readlane-broadcast gemm (~35us). R14: fgather (gather+next-gemm).
// R15: 4-chain epilogue FAILED (fgather still 86us, VALU 60%): epilogue is
//     ~200 wave-instr (64 readlane VALU + 64 ds_read + 64 FMA) vs ~50 for
//     the gather loop -- throughput-bound on VALU, not dep-chain.
// R16: (1) epilogue readlane -> LDS t-broadcast (ds_write_b128 quad once,
//     16x same-addr ds_read_b128): ~200 -> ~110 instr, VALU half, work
//     moved to LDS pipe. (2) segpool fused into rgather (2 atomics/wave).
//     (3) build grids: hist 1024, scatterB 256.
// ---------------------------------------------------------------------------

#define NBK 391          // ceil(100000/256) buckets; arrays padded to 512

__device__ __forceinline__ float bcastf(float v, int l) {
    return __int_as_float(__builtin_amdgcn_readlane(__float_as_int(v), l));
}

// LDS histogram of dst>>8, merged to global.
__global__ void hist_kernel(const int* __restrict__ dst,
                            int* __restrict__ bcnt, int ne) {
    __shared__ int h[512];
    for (int i = threadIdx.x; i < 512; i += blockDim.x) h[i] = 0;
    __syncthreads();
    int stride = gridDim.x * blockDim.x;
    for (int e = blockIdx.x * blockDim.x + threadIdx.x; e < ne; e += stride)
        atomicAdd(&h[dst[e] >> 8], 1);
    __syncthreads();
    for (int i = threadIdx.x; i < 512; i += blockDim.x)
        if (h[i]) atomicAdd(&bcnt[i], h[i]);
}

// One block: exclusive scan of bucket counts -> bbase[0..nb], seed gcur.
__global__ void bscan_kernel(const int* __restrict__ bcnt,
                             int* __restrict__ bbase,
                             int* __restrict__ gcur, int nb, int ne) {
    __shared__ int sh[512];
    int t = threadIdx.x;
    int v = (t < nb) ? bcnt[t] : 0;
    sh[t] = v;
    __syncthreads();
    for (int off = 1; off < 512; off <<= 1) {
        int u = (t >= off) ? sh[t - off] : 0;
        __syncthreads();
        sh[t] += u;
        __syncthreads();
    }
    if (t < nb) {
        int e = sh[t] - v;
        bbase[t] = e;
        gcur[t] = e;
    }
    if (t == 0) bbase[nb] = ne;
}

// Redistribute edges into bucket regions. packed = {(local8<<24)|src17, w}.
__global__ void scatterB_kernel(const int* __restrict__ src,
                                const int* __restrict__ dst,
                                const float* __restrict__ ew,
                                int* __restrict__ gcur,
                                int2* __restrict__ packed, int ne) {
    __shared__ int h[512];
    __shared__ int cur[512];
    int chunk = (ne + gridDim.x - 1) / gridDim.x;
    int e0 = blockIdx.x * chunk;
    int e1 = e0 + chunk; if (e1 > ne) e1 = ne;
    for (int i = threadIdx.x; i < 512; i += blockDim.x) h[i] = 0;
    __syncthreads();
    for (int e = e0 + threadIdx.x; e < e1; e += blockDim.x)
        atomicAdd(&h[dst[e] >> 8], 1);
    __syncthreads();
    for (int i = threadIdx.x; i < 512; i += blockDim.x)
        cur[i] = h[i] ? atomicAdd(&gcur[i], h[i]) : 0;
    __syncthreads();
    for (int e = e0 + threadIdx.x; e < e1; e += blockDim.x) {
        int d = dst[e];
        int pos = atomicAdd(&cur[d >> 8], 1);   // LDS atomic
        int2 v;
        v.x = ((d & 255) << 24) | src[e];       // src < 2^17, fits
        v.y = __float_as_int(ew[e]);
        packed[pos] = v;
    }
}

// One WG per bucket (256 nodes): count/scan/scatter in LDS, emit rptr/cnt/
// dinv + final CSR in the bucket's L2-hot window. No global atomics.
__global__ void bucket_build_kernel(const int2* __restrict__ packed,
                                    const int* __restrict__ bbase,
                                    int* __restrict__ rptr,
                                    int* __restrict__ cnt,
                                    float* __restrict__ dinv,
                                    int2* __restrict__ csr, int n) {
    __shared__ int cl[256];
    __shared__ int sc[256];
    __shared__ int cur[256];
    int b = blockIdx.x;
    int t = threadIdx.x;
    int node0 = b << 8;
    int nn = n - node0; if (nn > 256) nn = 256;
    int ebase = bbase[b];
    int m = bbase[b + 1] - ebase;
    cl[t] = 0;
    __syncthreads();
    for (int j = t; j < m; j += 256) {
        int local = ((unsigned)packed[ebase + j].x) >> 24;
        atomicAdd(&cl[local], 1);               // LDS atomic
    }
    __syncthreads();
    int c = cl[t];
    sc[t] = c;
    __syncthreads();
    for (int off = 1; off < 256; off <<= 1) {
        int u = (t >= off) ? sc[t - off] : 0;
        __syncthreads();
        sc[t] += u;
        __syncthreads();
    }
    int base = ebase + sc[t] - c;               // global CSR row start
    cur[t] = base;
    if (t < nn) {
        rptr[node0 + t] = base;
        cnt[node0 + t] = c;
    }
    __syncthreads();
    for (int j = t; j < m; j += 256) {
        int2 p = packed[ebase + j];
        int local = ((unsigned)p.x) >> 24;
        int pos = atomicAdd(&cur[local], 1);    // LDS atomic
        int2 v;
        v.x = p.x & 0x00FFFFFF;
        v.y = p.y;
        csr[pos] = v;
    }
    __syncthreads();
    if (t < nn) {
        float s = 0.0f;
        for (int j = base; j < base + c; ++j)
            s += __int_as_float(csr[j].y);
        dinv[node0 + t] = 1.0f / sqrtf(s + 1.0f);
    }
}

// GEMM via readlane broadcast (R13, proven).
template <bool RELU>
__global__ void __launch_bounds__(256, 4)
gemm_rl_kernel(const float* __restrict__ X, const float* W,
               const float* __restrict__ dinv, float* __restrict__ Ts,
               int n) {
    __shared__ float Wl[4096];
    {
        const float4* Wv = (const float4*)W;
        float4* Lv = (float4*)Wl;
        for (int i = threadIdx.x; i < 1024; i += 256) Lv[i] = Wv[i];
    }
    __syncthreads();
    int lane = threadIdx.x & 63;
    int wid  = (blockIdx.x * blockDim.x + threadIdx.x) >> 6;
    int nw   = (gridDim.x * blockDim.x) >> 6;
    int lrow = lane >> 4;
    int lcol = (lane & 15) * 4;
    for (int r0 = wid * 4; r0 + 4 <= n; r0 += nw * 4) {
        float4 xv = *(const float4*)&X[(size_t)(r0 + lrow) * 64 + lcol];
        if (RELU) {
            xv.x = fmaxf(xv.x, 0.f); xv.y = fmaxf(xv.y, 0.f);
            xv.z = fmaxf(xv.z, 0.f); xv.w = fmaxf(xv.w, 0.f);
        }
        float a0 = 0.f, a1 = 0.f, a2 = 0.f, a3 = 0.f;
#pragma unroll
        for (int k4 = 0; k4 < 16; ++k4) {
            float w0 = Wl[(4 * k4 + 0) * 64 + lane];
            float w1 = Wl[(4 * k4 + 1) * 64 + lane];
            float w2 = Wl[(4 * k4 + 2) * 64 + lane];
            float w3 = Wl[(4 * k4 + 3) * 64 + lane];
            a0 = fmaf(bcastf(xv.x, k4), w0, a0);
            a0 = fmaf(bcastf(xv.y, k4), w1, a0);
            a0 = fmaf(bcastf(xv.z, k4), w2, a0);
            a0 = fmaf(bcastf(xv.w, k4), w3, a0);
            a1 = fmaf(bcastf(xv.x, 16 + k4), w0, a1);
            a1 = fmaf(bcastf(xv.y, 16 + k4), w1, a1);
            a1 = fmaf(bcastf(xv.z, 16 + k4), w2, a1);
            a1 = fmaf(bcastf(xv.w, 16 + k4), w3, a1);
            a2 = fmaf(bcastf(xv.x, 32 + k4), w0, a2);
            a2 = fmaf(bcastf(xv.y, 32 + k4), w1, a2);
            a2 = fmaf(bcastf(xv.z, 32 + k4), w2, a2);
            a2 = fmaf(bcastf(xv.w, 32 + k4), w3, a2);
            a3 = fmaf(bcastf(xv.x, 48 + k4), w0, a3);
            a3 = fmaf(bcastf(xv.y, 48 + k4), w1, a3);
            a3 = fmaf(bcastf(xv.z, 48 + k4), w2, a3);
            a3 = fmaf(bcastf(xv.w, 48 + k4), w3, a3);
        }
        Ts[(size_t)(r0 + 0) * 64 + lane] = a0 * dinv[r0 + 0];
        Ts[(size_t)(r0 + 1) * 64 + lane] = a1 * dinv[r0 + 1];
        Ts[(size_t)(r0 + 2) * 64 + lane] = a2 * dinv[r0 + 2];
        Ts[(size_t)(r0 + 3) * 64 + lane] = a3 * dinv[r0 + 3];
    }
    if (wid == 0) {
        for (int r = (n & ~3); r < n; ++r) {
            const float4* xr = (const float4*)(X + (size_t)r * 64);
            float acc = 0.f;
#pragma unroll
            for (int k4 = 0; k4 < 16; ++k4) {
                float4 a = xr[k4];
                if (RELU) {
                    a.x = fmaxf(a.x, 0.f); a.y = fmaxf(a.y, 0.f);
                    a.z = fmaxf(a.z, 0.f); a.w = fmaxf(a.w, 0.f);
                }
                acc = fmaf(a.x, Wl[(4 * k4 + 0) * 64 + lane], acc);
                acc = fmaf(a.y, Wl[(4 * k4 + 1) * 64 + lane], acc);
                acc = fmaf(a.z, Wl[(4 * k4 + 2) * 64 + lane], acc);
                acc = fmaf(a.w, Wl[(4 * k4 + 3) * 64 + lane], acc);
            }
            Ts[(size_t)r * 64 + lane] = acc * dinv[r];
        }
    }
}

// Fused gather + next-layer gemm. R16 epilogue: t quad written once to a
// per-wave LDS buffer (ds_write_b128 by sub 0), then 16 same-addr
// ds_read_b128 broadcasts feed the 64-FMA dot -- no readlanes (VALU halved).
__global__ void __launch_bounds__(256, 4)
fgather_kernel(const int2* __restrict__ csr,
               const int* __restrict__ rptr,
               const int* __restrict__ cnt,
               const float* __restrict__ dinv,
               const float* __restrict__ b,
               const float* __restrict__ Ts_in,
               const float* Wn,
               float* __restrict__ Ts_out, int n) {
    __shared__ float Wl[4096];
    __shared__ float tbuf[4][64];
    {
        const float4* Wv = (const float4*)Wn;
        float4* Lv = (float4*)Wl;
        for (int i = threadIdx.x; i < 1024; i += 256) Lv[i] = Wv[i];
    }
    __syncthreads();
    int lane = threadIdx.x & 63;
    int w = threadIdx.x >> 6;
    int r = (int)(((size_t)blockIdx.x * blockDim.x + threadIdx.x) >> 6);
    if (r >= n) return;
    int sub = lane >> 4;
    int cl  = lane & 15;
    int start = rptr[r];
    int m = cnt[r];
    float4 a0 = {0.f, 0.f, 0.f, 0.f};
    float4 a1 = {0.f, 0.f, 0.f, 0.f};
    float4 a2 = {0.f, 0.f, 0.f, 0.f};
    float4 a3 = {0.f, 0.f, 0.f, 0.f};
    int j = sub;
    for (; j + 12 < m; j += 16) {
        int2 e0 = csr[start + j];
        int2 e1 = csr[start + j + 4];
        int2 e2 = csr[start + j + 8];
        int2 e3 = csr[start + j + 12];
        float w0 = __int_as_float(e0.y);
        float w1 = __int_as_float(e1.y);
        float w2 = __int_as_float(e2.y);
        float w3 = __int_as_float(e3.y);
        float4 t0 = *(const float4*)&Ts_in[(size_t)e0.x * 64 + cl * 4];
        float4 t1 = *(const float4*)&Ts_in[(size_t)e1.x * 64 + cl * 4];
        float4 t2 = *(const float4*)&Ts_in[(size_t)e2.x * 64 + cl * 4];
        float4 t3 = *(const float4*)&Ts_in[(size_t)e3.x * 64 + cl * 4];
        a0.x = fmaf(t0.x, w0, a0.x); a0.y = fmaf(t0.y, w0, a0.y);
        a0.z = fmaf(t0.z, w0, a0.z); a0.w = fmaf(t0.w, w0, a0.w);
        a1.x = fmaf(t1.x, w1, a1.x); a1.y = fmaf(t1.y, w1, a1.y);
        a1.z = fmaf(t1.z, w1, a1.z); a1.w = fmaf(t1.w, w1, a1.w);
        a2.x = fmaf(t2.x, w2, a2.x); a2.y = fmaf(t2.y, w2, a2.y);
        a2.z = fmaf(t2.z, w2, a2.z); a2.w = fmaf(t2.w, w2, a2.w);
        a3.x = fmaf(t3.x, w3, a3.x); a3.y = fmaf(t3.y, w3, a3.y);
        a3.z = fmaf(t3.z, w3, a3.z); a3.w = fmaf(t3.w, w3, a3.w);
    }
    for (; j < m; j += 4) {
        int2 e0 = csr[start + j];
        float w0 = __int_as_float(e0.y);
        float4 t0 = *(const float4*)&Ts_in[(size_t)e0.x * 64 + cl * 4];
        a0.x = fmaf(t0.x, w0, a0.x); a0.y = fmaf(t0.y, w0, a0.y);
        a0.z = fmaf(t0.z, w0, a0.z); a0.w = fmaf(t0.w, w0, a0.w);
    }
    a0.x += a1.x + a2.x + a3.x;
    a0.y += a1.y + a2.y + a3.y;
    a0.z += a1.z + a2.z + a3.z;
    a0.w += a1.w + a2.w + a3.w;
#pragma unroll
    for (int off = 16; off < 64; off <<= 1) {
        a0.x += __shfl_xor(a0.x, off);
        a0.y += __shfl_xor(a0.y, off);
        a0.z += __shfl_xor(a0.z, off);
        a0.w += __shfl_xor(a0.w, off);
    }
    float dv = dinv[r];
    float4 ts = *(const float4*)&Ts_in[(size_t)r * 64 + cl * 4];
    float4 bb = *(const float4*)&b[cl * 4];
    if (sub == 0) {
        float4 tq;
        tq.x = fmaxf(fmaf(dv, a0.x + ts.x, bb.x), 0.f);
        tq.y = fmaxf(fmaf(dv, a0.y + ts.y, bb.y), 0.f);
        tq.z = fmaxf(fmaf(dv, a0.z + ts.z, bb.z), 0.f);
        tq.w = fmaxf(fmaf(dv, a0.w + ts.w, bb.w), 0.f);
        *(float4*)&tbuf[w][cl * 4] = tq;    // ds_write_b128
    }
    // same-wave LDS RAW: compiler inserts lgkmcnt wait
    float c0 = 0.f, c1 = 0.f, c2 = 0.f, c3 = 0.f;
#pragma unroll
    for (int q = 0; q < 16; ++q) {
        float4 tq = *(const float4*)&tbuf[w][q * 4];   // same-addr broadcast
        c0 = fmaf(tq.x, Wl[(4 * q + 0) * 64 + lane], c0);
        c1 = fmaf(tq.y, Wl[(4 * q + 1) * 64 + lane], c1);
        c2 = fmaf(tq.z, Wl[(4 * q + 2) * 64 + lane], c2);
        c3 = fmaf(tq.w, Wl[(4 * q + 3) * 64 + lane], c3);
    }
    Ts_out[(size_t)r * 64 + lane] = ((c0 + c1) + (c2 + c3)) * dv;
}

// Final layer: gather + readout MLP + segment-pool fused. A row lives in
// registers/LDS only; lane0 atomics gsum/gcnt (2 atomics per wave).
__global__ void __launch_bounds__(256, 4)
rgather_kernel(const int2* __restrict__ csr,
               const int* __restrict__ rptr,
               const int* __restrict__ cnt,
               const float* __restrict__ dinv,
               const float* __restrict__ b,
               const float* __restrict__ Ts,
               const float* Wr0, const float* br0,
               const float* Wr1, const float* br1,
               const int* __restrict__ batch,
               float* __restrict__ gsum,
               float* __restrict__ gcnt, int n) {
    __shared__ float Wl[64 * 32];
    __shared__ float w1s[32];
    __shared__ float b0s[32];
    __shared__ float tbuf[4][64];
    {
        const float4* Wv = (const float4*)Wr0;
        float4* Lv = (float4*)Wl;
        for (int i = threadIdx.x; i < 512; i += 256) Lv[i] = Wv[i];
        if (threadIdx.x < 32) {
            w1s[threadIdx.x] = Wr1[threadIdx.x];
            b0s[threadIdx.x] = br0[threadIdx.x];
        }
    }
    __syncthreads();
    int lane = threadIdx.x & 63;
    int w = threadIdx.x >> 6;
    int r = (int)(((size_t)blockIdx.x * blockDim.x + threadIdx.x) >> 6);
    if (r >= n) return;
    int sub = lane >> 4;
    int cl  = lane & 15;
    int start = rptr[r];
    int m = cnt[r];
    float4 a0 = {0.f, 0.f, 0.f, 0.f};
    float4 a1 = {0.f, 0.f, 0.f, 0.f};
    float4 a2 = {0.f, 0.f, 0.f, 0.f};
    float4 a3 = {0.f, 0.f, 0.f, 0.f};
    int j = sub;
    for (; j + 12 < m; j += 16) {
        int2 e0 = csr[start + j];
        int2 e1 = csr[start + j + 4];
        int2 e2 = csr[start + j + 8];
        int2 e3 = csr[start + j + 12];
        float w0 = __int_as_float(e0.y);
        float w1 = __int_as_float(e1.y);
        float w2 = __int_as_float(e2.y);
        float w3 = __int_as_float(e3.y);
        float4 t0 = *(const float4*)&Ts[(size_t)e0.x * 64 + cl * 4];
        float4 t1 = *(const float4*)&Ts[(size_t)e1.x * 64 + cl * 4];
        float4 t2 = *(const float4*)&Ts[(size_t)e2.x * 64 + cl * 4];
        float4 t3 = *(const float4*)&Ts[(size_t)e3.x * 64 + cl * 4];
        a0.x = fmaf(t0.x, w0, a0.x); a0.y = fmaf(t0.y, w0, a0.y);
        a0.z = fmaf(t0.z, w0, a0.z); a0.w = fmaf(t0.w, w0, a0.w);
        a1.x = fmaf(t1.x, w1, a1.x); a1.y = fmaf(t1.y, w1, a1.y);
        a1.z = fmaf(t1.z, w1, a1.z); a1.w = fmaf(t1.w, w1, a1.w);
        a2.x = fmaf(t2.x, w2, a2.x); a2.y = fmaf(t2.y, w2, a2.y);
        a2.z = fmaf(t2.z, w2, a2.z); a2.w = fmaf(t2.w, w2, a2.w);
        a3.x = fmaf(t3.x, w3, a3.x); a3.y = fmaf(t3.y, w3, a3.y);
        a3.z = fmaf(t3.z, w3, a3.z); a3.w = fmaf(t3.w, w3, a3.w);
    }
    for (; j < m; j += 4) {
        int2 e0 = csr[start + j];
        float w0 = __int_as_float(e0.y);
        float4 t0 = *(const float4*)&Ts[(size_t)e0.x * 64 + cl * 4];
        a0.x = fmaf(t0.x, w0, a0.x); a0.y = fmaf(t0.y, w0, a0.y);
        a0.z = fmaf(t0.z, w0, a0.z); a0.w = fmaf(t0.w, w0, a0.w);
    }
    a0.x += a1.x + a2.x + a3.x;
    a0.y += a1.y + a2.y + a3.y;
    a0.z += a1.z + a2.z + a3.z;
    a0.w += a1.w + a2.w + a3.w;
#pragma unroll
    for (int off = 16; off < 64; off <<= 1) {
        a0.x += __shfl_xor(a0.x, off);
        a0.y += __shfl_xor(a0.y, off);
        a0.z += __shfl_xor(a0.z, off);
        a0.w += __shfl_xor(a0.w, off);
    }
    float dv = dinv[r];
    float4 ts = *(const float4*)&Ts[(size_t)r * 64 + cl * 4];
    float4 bb = *(const float4*)&b[cl * 4];
    if (sub == 0) {
        float4 tq;
        tq.x = fmaf(dv, a0.x + ts.x, bb.x);   // A row (no relu, last layer)
        tq.y = fmaf(dv, a0.y + ts.y, bb.y);
        tq.z = fmaf(dv, a0.z + ts.z, bb.z);
        tq.w = fmaf(dv, a0.w + ts.w, bb.w);
        *(float4*)&tbuf[w][cl * 4] = tq;
    }
    int hj = lane & 31;
    float c0 = 0.f, c1 = 0.f, c2 = 0.f, c3 = 0.f;
#pragma unroll
    for (int q = 0; q < 16; ++q) {
        float4 tq = *(const float4*)&tbuf[w][q * 4];
        c0 = fmaf(tq.x, Wl[(4 * q + 0) * 32 + hj], c0);
        c1 = fmaf(tq.y, Wl[(4 * q + 1) * 32 + hj], c1);
        c2 = fmaf(tq.z, Wl[(4 * q + 2) * 32 + hj], c2);
        c3 = fmaf(tq.w, Wl[(4 * q + 3) * 32 + hj], c3);
    }
    float h = fmaxf(((c0 + c1) + (c2 + c3)) + b0s[hj], 0.f);
    float p = h * w1s[hj];
#pragma unroll
    for (int off = 1; off < 32; off <<= 1) p += __shfl_xor(p, off);
    if (lane == 0) {
        int g = batch[r];
        atomicAdd(&gsum[g], p + br1[0]);
        atomicAdd(&gcnt[g], 1.0f);
    }
}

__global__ void pool_fin_kernel(const float* __restrict__ gsum,
                                const float* __restrict__ gcnt,
                                float* __restrict__ out, int ng) {
    int g = blockIdx.x * blockDim.x + threadIdx.x;
    if (g < ng) out[g] = gsum[g] / fmaxf(gcnt[g], 1.0f);
}

extern "C" void kernel_launch(void* const* d_in, const int* in_sizes, int n_in,
                              void* d_out, int out_size, void* d_ws, size_t ws_size,
                              hipStream_t stream) {
    const float* x    = (const float*)d_in[0];
    const int*   ei   = (const int*)d_in[1];
    const float* ew   = (const float*)d_in[2];
    const int*   batch= (const int*)d_in[3];
    const float* W0   = (const float*)d_in[4];
    const float* b0   = (const float*)d_in[5];
    const float* W1   = (const float*)d_in[6];
    const float* b1   = (const float*)d_in[7];
    const float* W2   = (const float*)d_in[8];
    const float* b2   = (const float*)d_in[9];
    const float* Wr0  = (const float*)d_in[10];
    const float* br0  = (const float*)d_in[11];
    const float* Wr1  = (const float*)d_in[12];
    const float* br1  = (const float*)d_in[13];
    float* out = (float*)d_out;

    int n  = in_sizes[0] / 64;   // 100000
    int ne = in_sizes[1] / 2;    // 1600000
    int ng = out_size;           // 256
    const int* srcv = ei;
    const int* dstv = ei + ne;
    int nbk = (n + 255) >> 8;    // 391

    char* ws = (char*)d_ws;
    size_t off = 0;
    auto alloc = [&](size_t bytes) {
        void* p = ws + off;
        off += (bytes + 255) & ~(size_t)255;
        return p;
    };
    float* Ts     = (float*)alloc((size_t)n * 64 * sizeof(float));
    float* A      = (float*)alloc((size_t)n * 64 * sizeof(float));
    float* dinv   = (float*)alloc((size_t)n * sizeof(float));
    int*   cnt    = (int*)alloc((size_t)n * sizeof(int));
    int*   rptr   = (int*)alloc((size_t)n * sizeof(int));
    int*   bcnt   = (int*)alloc(520 * sizeof(int));
    int*   bbase  = (int*)alloc(520 * sizeof(int));
    int*   gcur   = (int*)alloc(520 * sizeof(int));
    int2*  csr    = (int2*)alloc((size_t)ne * sizeof(int2));
    float* gsum   = (float*)alloc((size_t)ng * sizeof(float));
    float* gcnt   = (float*)alloc((size_t)ng * sizeof(float));
    // packed aliases Ts: consumed by bucket_build before first gemm writes Ts.
    int2*  packed = (int2*)Ts;
    (void)ws_size;

    hipMemsetAsync(bcnt, 0, 520 * sizeof(int), stream);
    hipMemsetAsync(gsum, 0, (size_t)ng * sizeof(float), stream);
    hipMemsetAsync(gcnt, 0, (size_t)ng * sizeof(float), stream);

    hist_kernel<<<1024, 256, 0, stream>>>(dstv, bcnt, ne);
    bscan_kernel<<<1, 512, 0, stream>>>(bcnt, bbase, gcur, nbk, ne);
    scatterB_kernel<<<256, 256, 0, stream>>>(srcv, dstv, ew, gcur, packed, ne);
    bucket_build_kernel<<<nbk, 256, 0, stream>>>(packed, bbase, rptr, cnt,
                                                 dinv, csr, n);

    const int gemm_blocks = 2048;
    unsigned gat_blocks = (unsigned)(((size_t)n * 64 + 255) / 256);

    // gemm0: Ts = x@W0*dinv
    gemm_rl_kernel<false><<<gemm_blocks, 256, 0, stream>>>(x, W0, dinv, Ts, n);
    // layer1: A-buf <- relu(gather(Ts)+b0) @ W1 * dinv
    fgather_kernel<<<gat_blocks, 256, 0, stream>>>(csr, rptr, cnt, dinv, b0,
                                                   Ts, W1, A, n);
    // layer2: Ts <- relu(gather(A-buf)+b1) @ W2 * dinv
    fgather_kernel<<<gat_blocks, 256, 0, stream>>>(csr, rptr, cnt, dinv, b1,
                                                   A, W2, Ts, n);
    // layer3 + readout + pool: atomics into gsum/gcnt
    rgather_kernel<<<gat_blocks, 256, 0, stream>>>(csr, rptr, cnt, dinv, b2,
                                                   Ts, Wr0, br0, Wr1, br1,
                                                   batch, gsum, gcnt, n);
    pool_fin_kernel<<<(ng + 255) / 256, 256, 0, stream>>>(gsum, gcnt, out, ng);
}

// Round 17
// 379.880 us; speedup vs baseline: 1.9729x; 1.9729x over previous
//
#include <hip/hip_runtime.h>

// ---------------------------------------------------------------------------
// Petri_GCN: 3x GCNConv(64->64) + MLP readout (64->32->1) + segment-mean pool
// All fp32 (abs threshold forbids bf16/MFMA; no fp32 MFMA on CDNA4).
// R1: CSR-by-dst + gather. R3: Ts=(X@W)*dinv; gather pure-write.
// R5: bucketed CSR build. R8-R12: gemm shape search; spill lessons
//     (scratch = WRITE_SIZE blowup; don't fight the register allocator).
// R13: readlane-broadcast gemm (~35us); gather is L3-BW-bound (~64.6us for
//     410MB logical random 256B reads -- near floor for this access pattern).
// R14/R15: fgather (gather + next-layer gemm fused); epilogue is VALU-
//     throughput-bound (~+21us/layer), cheaper than separate gemm (+35us).
// R16 REGRESSION: segment-pool atomics fused into rgather -> 490us. batch
//     is SORTED: ~390 waves/graph hit the SAME gsum dword simultaneously =
//     same-address RMW convoy (R2's lesson). RULE: sorted group ids =>
//     wave-segmented pre-reduction before ANY global atomic.
// R17: revert rgather to svbuf store + segpool kernel (R15 proven); keep
//     R16's LDS-broadcast epilogues and build grids.
// ---------------------------------------------------------------------------

#define NBK 391          // ceil(100000/256) buckets; arrays padded to 512

__device__ __forceinline__ float bcastf(float v, int l) {
    return __int_as_float(__builtin_amdgcn_readlane(__float_as_int(v), l));
}

// LDS histogram of dst>>8, merged to global.
__global__ void hist_kernel(const int* __restrict__ dst,
                            int* __restrict__ bcnt, int ne) {
    __shared__ int h[512];
    for (int i = threadIdx.x; i < 512; i += blockDim.x) h[i] = 0;
    __syncthreads();
    int stride = gridDim.x * blockDim.x;
    for (int e = blockIdx.x * blockDim.x + threadIdx.x; e < ne; e += stride)
        atomicAdd(&h[dst[e] >> 8], 1);
    __syncthreads();
    for (int i = threadIdx.x; i < 512; i += blockDim.x)
        if (h[i]) atomicAdd(&bcnt[i], h[i]);
}

// One block: exclusive scan of bucket counts -> bbase[0..nb], seed gcur.
__global__ void bscan_kernel(const int* __restrict__ bcnt,
                             int* __restrict__ bbase,
                             int* __restrict__ gcur, int nb, int ne) {
    __shared__ int sh[512];
    int t = threadIdx.x;
    int v = (t < nb) ? bcnt[t] : 0;
    sh[t] = v;
    __syncthreads();
    for (int off = 1; off < 512; off <<= 1) {
        int u = (t >= off) ? sh[t - off] : 0;
        __syncthreads();
        sh[t] += u;
        __syncthreads();
    }
    if (t < nb) {
        int e = sh[t] - v;
        bbase[t] = e;
        gcur[t] = e;
    }
    if (t == 0) bbase[nb] = ne;
}

// Redistribute edges into bucket regions. packed = {(local8<<24)|src17, w}.
__global__ void scatterB_kernel(const int* __restrict__ src,
                                const int* __restrict__ dst,
                                const float* __restrict__ ew,
                                int* __restrict__ gcur,
                                int2* __restrict__ packed, int ne) {
    __shared__ int h[512];
    __shared__ int cur[512];
    int chunk = (ne + gridDim.x - 1) / gridDim.x;
    int e0 = blockIdx.x * chunk;
    int e1 = e0 + chunk; if (e1 > ne) e1 = ne;
    for (int i = threadIdx.x; i < 512; i += blockDim.x) h[i] = 0;
    __syncthreads();
    for (int e = e0 + threadIdx.x; e < e1; e += blockDim.x)
        atomicAdd(&h[dst[e] >> 8], 1);
    __syncthreads();
    for (int i = threadIdx.x; i < 512; i += blockDim.x)
        cur[i] = h[i] ? atomicAdd(&gcur[i], h[i]) : 0;
    __syncthreads();
    for (int e = e0 + threadIdx.x; e < e1; e += blockDim.x) {
        int d = dst[e];
        int pos = atomicAdd(&cur[d >> 8], 1);   // LDS atomic
        int2 v;
        v.x = ((d & 255) << 24) | src[e];       // src < 2^17, fits
        v.y = __float_as_int(ew[e]);
        packed[pos] = v;
    }
}

// One WG per bucket (256 nodes): count/scan/scatter in LDS, emit rptr/cnt/
// dinv + final CSR in the bucket's L2-hot window. No global atomics.
__global__ void bucket_build_kernel(const int2* __restrict__ packed,
                                    const int* __restrict__ bbase,
                                    int* __restrict__ rptr,
                                    int* __restrict__ cnt,
                                    float* __restrict__ dinv,
                                    int2* __restrict__ csr, int n) {
    __shared__ int cl[256];
    __shared__ int sc[256];
    __shared__ int cur[256];
    int b = blockIdx.x;
    int t = threadIdx.x;
    int node0 = b << 8;
    int nn = n - node0; if (nn > 256) nn = 256;
    int ebase = bbase[b];
    int m = bbase[b + 1] - ebase;
    cl[t] = 0;
    __syncthreads();
    for (int j = t; j < m; j += 256) {
        int local = ((unsigned)packed[ebase + j].x) >> 24;
        atomicAdd(&cl[local], 1);               // LDS atomic
    }
    __syncthreads();
    int c = cl[t];
    sc[t] = c;
    __syncthreads();
    for (int off = 1; off < 256; off <<= 1) {
        int u = (t >= off) ? sc[t - off] : 0;
        __syncthreads();
        sc[t] += u;
        __syncthreads();
    }
    int base = ebase + sc[t] - c;               // global CSR row start
    cur[t] = base;
    if (t < nn) {
        rptr[node0 + t] = base;
        cnt[node0 + t] = c;
    }
    __syncthreads();
    for (int j = t; j < m; j += 256) {
        int2 p = packed[ebase + j];
        int local = ((unsigned)p.x) >> 24;
        int pos = atomicAdd(&cur[local], 1);    // LDS atomic
        int2 v;
        v.x = p.x & 0x00FFFFFF;
        v.y = p.y;
        csr[pos] = v;
    }
    __syncthreads();
    if (t < nn) {
        float s = 0.0f;
        for (int j = base; j < base + c; ++j)
            s += __int_as_float(csr[j].y);
        dinv[node0 + t] = 1.0f / sqrtf(s + 1.0f);
    }
}

// GEMM via readlane broadcast (R13, proven).
template <bool RELU>
__global__ void __launch_bounds__(256, 4)
gemm_rl_kernel(const float* __restrict__ X, const float* W,
               const float* __restrict__ dinv, float* __restrict__ Ts,
               int n) {
    __shared__ float Wl[4096];
    {
        const float4* Wv = (const float4*)W;
        float4* Lv = (float4*)Wl;
        for (int i = threadIdx.x; i < 1024; i += 256) Lv[i] = Wv[i];
    }
    __syncthreads();
    int lane = threadIdx.x & 63;
    int wid  = (blockIdx.x * blockDim.x + threadIdx.x) >> 6;
    int nw   = (gridDim.x * blockDim.x) >> 6;
    int lrow = lane >> 4;
    int lcol = (lane & 15) * 4;
    for (int r0 = wid * 4; r0 + 4 <= n; r0 += nw * 4) {
        float4 xv = *(const float4*)&X[(size_t)(r0 + lrow) * 64 + lcol];
        if (RELU) {
            xv.x = fmaxf(xv.x, 0.f); xv.y = fmaxf(xv.y, 0.f);
            xv.z = fmaxf(xv.z, 0.f); xv.w = fmaxf(xv.w, 0.f);
        }
        float a0 = 0.f, a1 = 0.f, a2 = 0.f, a3 = 0.f;
#pragma unroll
        for (int k4 = 0; k4 < 16; ++k4) {
            float w0 = Wl[(4 * k4 + 0) * 64 + lane];
            float w1 = Wl[(4 * k4 + 1) * 64 + lane];
            float w2 = Wl[(4 * k4 + 2) * 64 + lane];
            float w3 = Wl[(4 * k4 + 3) * 64 + lane];
            a0 = fmaf(bcastf(xv.x, k4), w0, a0);
            a0 = fmaf(bcastf(xv.y, k4), w1, a0);
            a0 = fmaf(bcastf(xv.z, k4), w2, a0);
            a0 = fmaf(bcastf(xv.w, k4), w3, a0);
            a1 = fmaf(bcastf(xv.x, 16 + k4), w0, a1);
            a1 = fmaf(bcastf(xv.y, 16 + k4), w1, a1);
            a1 = fmaf(bcastf(xv.z, 16 + k4), w2, a1);
            a1 = fmaf(bcastf(xv.w, 16 + k4), w3, a1);
            a2 = fmaf(bcastf(xv.x, 32 + k4), w0, a2);
            a2 = fmaf(bcastf(xv.y, 32 + k4), w1, a2);
            a2 = fmaf(bcastf(xv.z, 32 + k4), w2, a2);
            a2 = fmaf(bcastf(xv.w, 32 + k4), w3, a2);
            a3 = fmaf(bcastf(xv.x, 48 + k4), w0, a3);
            a3 = fmaf(bcastf(xv.y, 48 + k4), w1, a3);
            a3 = fmaf(bcastf(xv.z, 48 + k4), w2, a3);
            a3 = fmaf(bcastf(xv.w, 48 + k4), w3, a3);
        }
        Ts[(size_t)(r0 + 0) * 64 + lane] = a0 * dinv[r0 + 0];
        Ts[(size_t)(r0 + 1) * 64 + lane] = a1 * dinv[r0 + 1];
        Ts[(size_t)(r0 + 2) * 64 + lane] = a2 * dinv[r0 + 2];
        Ts[(size_t)(r0 + 3) * 64 + lane] = a3 * dinv[r0 + 3];
    }
    if (wid == 0) {
        for (int r = (n & ~3); r < n; ++r) {
            const float4* xr = (const float4*)(X + (size_t)r * 64);
            float acc = 0.f;
#pragma unroll
            for (int k4 = 0; k4 < 16; ++k4) {
                float4 a = xr[k4];
                if (RELU) {
                    a.x = fmaxf(a.x, 0.f); a.y = fmaxf(a.y, 0.f);
                    a.z = fmaxf(a.z, 0.f); a.w = fmaxf(a.w, 0.f);
                }
                acc = fmaf(a.x, Wl[(4 * k4 + 0) * 64 + lane], acc);
                acc = fmaf(a.y, Wl[(4 * k4 + 1) * 64 + lane], acc);
                acc = fmaf(a.z, Wl[(4 * k4 + 2) * 64 + lane], acc);
                acc = fmaf(a.w, Wl[(4 * k4 + 3) * 64 + lane], acc);
            }
            Ts[(size_t)r * 64 + lane] = acc * dinv[r];
        }
    }
}

// Fused gather + next-layer gemm, LDS-broadcast epilogue (R16).
__global__ void __launch_bounds__(256, 4)
fgather_kernel(const int2* __restrict__ csr,
               const int* __restrict__ rptr,
               const int* __restrict__ cnt,
               const float* __restrict__ dinv,
               const float* __restrict__ b,
               const float* __restrict__ Ts_in,
               const float* Wn,
               float* __restrict__ Ts_out, int n) {
    __shared__ float Wl[4096];
    __shared__ float tbuf[4][64];
    {
        const float4* Wv = (const float4*)Wn;
        float4* Lv = (float4*)Wl;
        for (int i = threadIdx.x; i < 1024; i += 256) Lv[i] = Wv[i];
    }
    __syncthreads();
    int lane = threadIdx.x & 63;
    int w = threadIdx.x >> 6;
    int r = (int)(((size_t)blockIdx.x * blockDim.x + threadIdx.x) >> 6);
    if (r >= n) return;
    int sub = lane >> 4;
    int cl  = lane & 15;
    int start = rptr[r];
    int m = cnt[r];
    float4 a0 = {0.f, 0.f, 0.f, 0.f};
    float4 a1 = {0.f, 0.f, 0.f, 0.f};
    float4 a2 = {0.f, 0.f, 0.f, 0.f};
    float4 a3 = {0.f, 0.f, 0.f, 0.f};
    int j = sub;
    for (; j + 12 < m; j += 16) {
        int2 e0 = csr[start + j];
        int2 e1 = csr[start + j + 4];
        int2 e2 = csr[start + j + 8];
        int2 e3 = csr[start + j + 12];
        float w0 = __int_as_float(e0.y);
        float w1 = __int_as_float(e1.y);
        float w2 = __int_as_float(e2.y);
        float w3 = __int_as_float(e3.y);
        float4 t0 = *(const float4*)&Ts_in[(size_t)e0.x * 64 + cl * 4];
        float4 t1 = *(const float4*)&Ts_in[(size_t)e1.x * 64 + cl * 4];
        float4 t2 = *(const float4*)&Ts_in[(size_t)e2.x * 64 + cl * 4];
        float4 t3 = *(const float4*)&Ts_in[(size_t)e3.x * 64 + cl * 4];
        a0.x = fmaf(t0.x, w0, a0.x); a0.y = fmaf(t0.y, w0, a0.y);
        a0.z = fmaf(t0.z, w0, a0.z); a0.w = fmaf(t0.w, w0, a0.w);
        a1.x = fmaf(t1.x, w1, a1.x); a1.y = fmaf(t1.y, w1, a1.y);
        a1.z = fmaf(t1.z, w1, a1.z); a1.w = fmaf(t1.w, w1, a1.w);
        a2.x = fmaf(t2.x, w2, a2.x); a2.y = fmaf(t2.y, w2, a2.y);
        a2.z = fmaf(t2.z, w2, a2.z); a2.w = fmaf(t2.w, w2, a2.w);
        a3.x = fmaf(t3.x, w3, a3.x); a3.y = fmaf(t3.y, w3, a3.y);
        a3.z = fmaf(t3.z, w3, a3.z); a3.w = fmaf(t3.w, w3, a3.w);
    }
    for (; j < m; j += 4) {
        int2 e0 = csr[start + j];
        float w0 = __int_as_float(e0.y);
        float4 t0 = *(const float4*)&Ts_in[(size_t)e0.x * 64 + cl * 4];
        a0.x = fmaf(t0.x, w0, a0.x); a0.y = fmaf(t0.y, w0, a0.y);
        a0.z = fmaf(t0.z, w0, a0.z); a0.w = fmaf(t0.w, w0, a0.w);
    }
    a0.x += a1.x + a2.x + a3.x;
    a0.y += a1.y + a2.y + a3.y;
    a0.z += a1.z + a2.z + a3.z;
    a0.w += a1.w + a2.w + a3.w;
#pragma unroll
    for (int off = 16; off < 64; off <<= 1) {
        a0.x += __shfl_xor(a0.x, off);
        a0.y += __shfl_xor(a0.y, off);
        a0.z += __shfl_xor(a0.z, off);
        a0.w += __shfl_xor(a0.w, off);
    }
    float dv = dinv[r];
    float4 ts = *(const float4*)&Ts_in[(size_t)r * 64 + cl * 4];
    float4 bb = *(const float4*)&b[cl * 4];
    if (sub == 0) {
        float4 tq;
        tq.x = fmaxf(fmaf(dv, a0.x + ts.x, bb.x), 0.f);
        tq.y = fmaxf(fmaf(dv, a0.y + ts.y, bb.y), 0.f);
        tq.z = fmaxf(fmaf(dv, a0.z + ts.z, bb.z), 0.f);
        tq.w = fmaxf(fmaf(dv, a0.w + ts.w, bb.w), 0.f);
        *(float4*)&tbuf[w][cl * 4] = tq;    // ds_write_b128
    }
    // same-wave LDS RAW: compiler inserts lgkmcnt wait
    float c0 = 0.f, c1 = 0.f, c2 = 0.f, c3 = 0.f;
#pragma unroll
    for (int q = 0; q < 16; ++q) {
        float4 tq = *(const float4*)&tbuf[w][q * 4];   // same-addr broadcast
        c0 = fmaf(tq.x, Wl[(4 * q + 0) * 64 + lane], c0);
        c1 = fmaf(tq.y, Wl[(4 * q + 1) * 64 + lane], c1);
        c2 = fmaf(tq.z, Wl[(4 * q + 2) * 64 + lane], c2);
        c3 = fmaf(tq.w, Wl[(4 * q + 3) * 64 + lane], c3);
    }
    Ts_out[(size_t)r * 64 + lane] = ((c0 + c1) + (c2 + c3)) * dv;
}

// Final layer: gather + readout MLP fused; lane0 writes per-node scalar
// svbuf[r] (NO atomics here -- R16 lesson: sorted batch => convoy).
__global__ void __launch_bounds__(256, 4)
rgather_kernel(const int2* __restrict__ csr,
               const int* __restrict__ rptr,
               const int* __restrict__ cnt,
               const float* __restrict__ dinv,
               const float* __restrict__ b,
               const float* __restrict__ Ts,
               const float* Wr0, const float* br0,
               const float* Wr1, const float* br1,
               float* __restrict__ svbuf, int n) {
    __shared__ float Wl[64 * 32];
    __shared__ float w1s[32];
    __shared__ float b0s[32];
    __shared__ float tbuf[4][64];
    {
        const float4* Wv = (const float4*)Wr0;
        float4* Lv = (float4*)Wl;
        for (int i = threadIdx.x; i < 512; i += 256) Lv[i] = Wv[i];
        if (threadIdx.x < 32) {
            w1s[threadIdx.x] = Wr1[threadIdx.x];
            b0s[threadIdx.x] = br0[threadIdx.x];
        }
    }
    __syncthreads();
    int lane = threadIdx.x & 63;
    int w = threadIdx.x >> 6;
    int r = (int)(((size_t)blockIdx.x * blockDim.x + threadIdx.x) >> 6);
    if (r >= n) return;
    int sub = lane >> 4;
    int cl  = lane & 15;
    int start = rptr[r];
    int m = cnt[r];
    float4 a0 = {0.f, 0.f, 0.f, 0.f};
    float4 a1 = {0.f, 0.f, 0.f, 0.f};
    float4 a2 = {0.f, 0.f, 0.f, 0.f};
    float4 a3 = {0.f, 0.f, 0.f, 0.f};
    int j = sub;
    for (; j + 12 < m; j += 16) {
        int2 e0 = csr[start + j];
        int2 e1 = csr[start + j + 4];
        int2 e2 = csr[start + j + 8];
        int2 e3 = csr[start + j + 12];
        float w0 = __int_as_float(e0.y);
        float w1 = __int_as_float(e1.y);
        float w2 = __int_as_float(e2.y);
        float w3 = __int_as_float(e3.y);
        float4 t0 = *(const float4*)&Ts[(size_t)e0.x * 64 + cl * 4];
        float4 t1 = *(const float4*)&Ts[(size_t)e1.x * 64 + cl * 4];
        float4 t2 = *(const float4*)&Ts[(size_t)e2.x * 64 + cl * 4];
        float4 t3 = *(const float4*)&Ts[(size_t)e3.x * 64 + cl * 4];
        a0.x = fmaf(t0.x, w0, a0.x); a0.y = fmaf(t0.y, w0, a0.y);
        a0.z = fmaf(t0.z, w0, a0.z); a0.w = fmaf(t0.w, w0, a0.w);
        a1.x = fmaf(t1.x, w1, a1.x); a1.y = fmaf(t1.y, w1, a1.y);
        a1.z = fmaf(t1.z, w1, a1.z); a1.w = fmaf(t1.w, w1, a1.w);
        a2.x = fmaf(t2.x, w2, a2.x); a2.y = fmaf(t2.y, w2, a2.y);
        a2.z = fmaf(t2.z, w2, a2.z); a2.w = fmaf(t2.w, w2, a2.w);
        a3.x = fmaf(t3.x, w3, a3.x); a3.y = fmaf(t3.y, w3, a3.y);
        a3.z = fmaf(t3.z, w3, a3.z); a3.w = fmaf(t3.w, w3, a3.w);
    }
    for (; j < m; j += 4) {
        int2 e0 = csr[start + j];
        float w0 = __int_as_float(e0.y);
        float4 t0 = *(const float4*)&Ts[(size_t)e0.x * 64 + cl * 4];
        a0.x = fmaf(t0.x, w0, a0.x); a0.y = fmaf(t0.y, w0, a0.y);
        a0.z = fmaf(t0.z, w0, a0.z); a0.w = fmaf(t0.w, w0, a0.w);
    }
    a0.x += a1.x + a2.x + a3.x;
    a0.y += a1.y + a2.y + a3.y;
    a0.z += a1.z + a2.z + a3.z;
    a0.w += a1.w + a2.w + a3.w;
#pragma unroll
    for (int off = 16; off < 64; off <<= 1) {
        a0.x += __shfl_xor(a0.x, off);
        a0.y += __shfl_xor(a0.y, off);
        a0.z += __shfl_xor(a0.z, off);
        a0.w += __shfl_xor(a0.w, off);
    }
    float dv = dinv[r];
    float4 ts = *(const float4*)&Ts[(size_t)r * 64 + cl * 4];
    float4 bb = *(const float4*)&b[cl * 4];
    if (sub == 0) {
        float4 tq;
        tq.x = fmaf(dv, a0.x + ts.x, bb.x);   // A row (no relu, last layer)
        tq.y = fmaf(dv, a0.y + ts.y, bb.y);
        tq.z = fmaf(dv, a0.z + ts.z, bb.z);
        tq.w = fmaf(dv, a0.w + ts.w, bb.w);
        *(float4*)&tbuf[w][cl * 4] = tq;
    }
    int hj = lane & 31;
    float c0 = 0.f, c1 = 0.f, c2 = 0.f, c3 = 0.f;
#pragma unroll
    for (int q = 0; q < 16; ++q) {
        float4 tq = *(const float4*)&tbuf[w][q * 4];
        c0 = fmaf(tq.x, Wl[(4 * q + 0) * 32 + hj], c0);
        c1 = fmaf(tq.y, Wl[(4 * q + 1) * 32 + hj], c1);
        c2 = fmaf(tq.z, Wl[(4 * q + 2) * 32 + hj], c2);
        c3 = fmaf(tq.w, Wl[(4 * q + 3) * 32 + hj], c3);
    }
    float h = fmaxf(((c0 + c1) + (c2 + c3)) + b0s[hj], 0.f);
    float p = h * w1s[hj];
#pragma unroll
    for (int off = 1; off < 32; off <<= 1) p += __shfl_xor(p, off);
    if (lane == 0) svbuf[r] = p + br1[0];
}

// Wave-segmented reduce of per-node scalars (batch sorted): heads atomically
// add per-run partials (~2 atomics/wave, no same-address convoy).
__global__ void segpool_kernel(const float* __restrict__ svbuf,
                               const int* __restrict__ batch,
                               float* __restrict__ gsum,
                               float* __restrict__ gcnt, int n) {
    int r = blockIdx.x * blockDim.x + threadIdx.x;
    int lane = threadIdx.x & 63;
    float sv = 0.0f;
    int g = -1;
    if (r < n) { sv = svbuf[r]; g = batch[r]; }
    float c = (r < n) ? 1.0f : 0.0f;
#pragma unroll
    for (int off = 1; off < 64; off <<= 1) {
        int   og = __shfl_down(g, off);
        float ov = __shfl_down(sv, off);
        float oc = __shfl_down(c, off);
        if ((lane + off) < 64 && og == g) { sv += ov; c += oc; }
    }
    int gprev = __shfl_up(g, 1);
    bool head = (lane == 0) || (gprev != g);
    if (head && g >= 0) {
        atomicAdd(&gsum[g], sv);
        atomicAdd(&gcnt[g], c);
    }
}

__global__ void pool_fin_kernel(const float* __restrict__ gsum,
                                const float* __restrict__ gcnt,
                                float* __restrict__ out, int ng) {
    int g = blockIdx.x * blockDim.x + threadIdx.x;
    if (g < ng) out[g] = gsum[g] / fmaxf(gcnt[g], 1.0f);
}

extern "C" void kernel_launch(void* const* d_in, const int* in_sizes, int n_in,
                              void* d_out, int out_size, void* d_ws, size_t ws_size,
                              hipStream_t stream) {
    const float* x    = (const float*)d_in[0];
    const int*   ei   = (const int*)d_in[1];
    const float* ew   = (const float*)d_in[2];
    const int*   batch= (const int*)d_in[3];
    const float* W0   = (const float*)d_in[4];
    const float* b0   = (const float*)d_in[5];
    const float* W1   = (const float*)d_in[6];
    const float* b1   = (const float*)d_in[7];
    const float* W2   = (const float*)d_in[8];
    const float* b2   = (const float*)d_in[9];
    const float* Wr0  = (const float*)d_in[10];
    const float* br0  = (const float*)d_in[11];
    const float* Wr1  = (const float*)d_in[12];
    const float* br1  = (const float*)d_in[13];
    float* out = (float*)d_out;

    int n  = in_sizes[0] / 64;   // 100000
    int ne = in_sizes[1] / 2;    // 1600000
    int ng = out_size;           // 256
    const int* srcv = ei;
    const int* dstv = ei + ne;
    int nbk = (n + 255) >> 8;    // 391

    char* ws = (char*)d_ws;
    size_t off = 0;
    auto alloc = [&](size_t bytes) {
        void* p = ws + off;
        off += (bytes + 255) & ~(size_t)255;
        return p;
    };
    float* Ts     = (float*)alloc((size_t)n * 64 * sizeof(float));
    float* A      = (float*)alloc((size_t)n * 64 * sizeof(float));
    float* dinv   = (float*)alloc((size_t)n * sizeof(float));
    float* svbuf  = (float*)alloc((size_t)n * sizeof(float));
    int*   cnt    = (int*)alloc((size_t)n * sizeof(int));
    int*   rptr   = (int*)alloc((size_t)n * sizeof(int));
    int*   bcnt   = (int*)alloc(520 * sizeof(int));
    int*   bbase  = (int*)alloc(520 * sizeof(int));
    int*   gcur   = (int*)alloc(520 * sizeof(int));
    int2*  csr    = (int2*)alloc((size_t)ne * sizeof(int2));
    float* gsum   = (float*)alloc((size_t)ng * sizeof(float));
    float* gcnt   = (float*)alloc((size_t)ng * sizeof(float));
    // packed aliases Ts: consumed by bucket_build before first gemm writes Ts.
    int2*  packed = (int2*)Ts;
    (void)ws_size;

    hipMemsetAsync(bcnt, 0, 520 * sizeof(int), stream);
    hipMemsetAsync(gsum, 0, (size_t)ng * sizeof(float), stream);
    hipMemsetAsync(gcnt, 0, (size_t)ng * sizeof(float), stream);

    hist_kernel<<<1024, 256, 0, stream>>>(dstv, bcnt, ne);
    bscan_kernel<<<1, 512, 0, stream>>>(bcnt, bbase, gcur, nbk, ne);
    scatterB_kernel<<<256, 256, 0, stream>>>(srcv, dstv, ew, gcur, packed, ne);
    bucket_build_kernel<<<nbk, 256, 0, stream>>>(packed, bbase, rptr, cnt,
                                                 dinv, csr, n);

    const int gemm_blocks = 2048;
    unsigned gat_blocks = (unsigned)(((size_t)n * 64 + 255) / 256);

    // gemm0: Ts = x@W0*dinv
    gemm_rl_kernel<false><<<gemm_blocks, 256, 0, stream>>>(x, W0, dinv, Ts, n);
    // layer1: A-buf <- relu(gather(Ts)+b0) @ W1 * dinv
    fgather_kernel<<<gat_blocks, 256, 0, stream>>>(csr, rptr, cnt, dinv, b0,
                                                   Ts, W1, A, n);
    // layer2: Ts <- relu(gather(A-buf)+b1) @ W2 * dinv
    fgather_kernel<<<gat_blocks, 256, 0, stream>>>(csr, rptr, cnt, dinv, b1,
                                                   A, W2, Ts, n);
    // layer3 + readout: svbuf[r] = MLP(gather(Ts)+b2)
    rgather_kernel<<<gat_blocks, 256, 0, stream>>>(csr, rptr, cnt, dinv, b2,
                                                   Ts, Wr0, br0, Wr1, br1,
                                                   svbuf, n);
    segpool_kernel<<<(n + 255) / 256, 256, 0, stream>>>(svbuf, batch,
                                                        gsum, gcnt, n);
    pool_fin_kernel<<<(ng + 255) / 256, 256, 0, stream>>>(gsum, gcnt, out, ng);
}

// Round 18
// 362.156 us; speedup vs baseline: 2.0694x; 1.0489x over previous
//
#include <hip/hip_runtime.h>

// ---------------------------------------------------------------------------
// Petri_GCN: 3x GCNConv(64->64) + MLP readout (64->32->1) + segment-mean pool
// All fp32 (abs threshold 1.2e-5 forbids bf16 anywhere; no fp32 MFMA on CDNA4).
// R1: CSR-by-dst + gather. R3: Ts=(X@W)*dinv; gather pure-write.
// R5: bucketed CSR build. R8-R12: gemm shape search; spill lessons.
// R13: readlane-broadcast gemm; gather is memory-system-bound (64.6us floor
//     for 410MB logical random 256B reads; fp32 mandatory).
// R14/R15: fgather/rgather fusion, readlane epilogue (+21us/layer, cheaper
//     than separate gemm +35us). R15 = 355.9us best known.
// R16 REGRESSION: pool atomics in rgather (sorted batch => same-dword RMW
//     convoy, 490us). RULE: sorted group ids => segmented pre-reduce first.
// R17: convoy fixed; exposed that R16's LDS-broadcast epilogue is WORSE than
//     readlane (95.3 vs 86us): VGPR=32 forbids prefetching the 16 ds_reads
//     -> serialized ~30-40cyc LDS latency each. Readlane VALU form wins.
// R18: epilogues reverted to R15 readlane; keep segpool + R16 build grids.
//     Near structural floor for this decomposition.
// ---------------------------------------------------------------------------

#define NBK 391          // ceil(100000/256) buckets; arrays padded to 512

__device__ __forceinline__ float bcastf(float v, int l) {
    return __int_as_float(__builtin_amdgcn_readlane(__float_as_int(v), l));
}

// LDS histogram of dst>>8, merged to global.
__global__ void hist_kernel(const int* __restrict__ dst,
                            int* __restrict__ bcnt, int ne) {
    __shared__ int h[512];
    for (int i = threadIdx.x; i < 512; i += blockDim.x) h[i] = 0;
    __syncthreads();
    int stride = gridDim.x * blockDim.x;
    for (int e = blockIdx.x * blockDim.x + threadIdx.x; e < ne; e += stride)
        atomicAdd(&h[dst[e] >> 8], 1);
    __syncthreads();
    for (int i = threadIdx.x; i < 512; i += blockDim.x)
        if (h[i]) atomicAdd(&bcnt[i], h[i]);
}

// One block: exclusive scan of bucket counts -> bbase[0..nb], seed gcur.
__global__ void bscan_kernel(const int* __restrict__ bcnt,
                             int* __restrict__ bbase,
                             int* __restrict__ gcur, int nb, int ne) {
    __shared__ int sh[512];
    int t = threadIdx.x;
    int v = (t < nb) ? bcnt[t] : 0;
    sh[t] = v;
    __syncthreads();
    for (int off = 1; off < 512; off <<= 1) {
        int u = (t >= off) ? sh[t - off] : 0;
        __syncthreads();
        sh[t] += u;
        __syncthreads();
    }
    if (t < nb) {
        int e = sh[t] - v;
        bbase[t] = e;
        gcur[t] = e;
    }
    if (t == 0) bbase[nb] = ne;
}

// Redistribute edges into bucket regions. packed = {(local8<<24)|src17, w}.
__global__ void scatterB_kernel(const int* __restrict__ src,
                                const int* __restrict__ dst,
                                const float* __restrict__ ew,
                                int* __restrict__ gcur,
                                int2* __restrict__ packed, int ne) {
    __shared__ int h[512];
    __shared__ int cur[512];
    int chunk = (ne + gridDim.x - 1) / gridDim.x;
    int e0 = blockIdx.x * chunk;
    int e1 = e0 + chunk; if (e1 > ne) e1 = ne;
    for (int i = threadIdx.x; i < 512; i += blockDim.x) h[i] = 0;
    __syncthreads();
    for (int e = e0 + threadIdx.x; e < e1; e += blockDim.x)
        atomicAdd(&h[dst[e] >> 8], 1);
    __syncthreads();
    for (int i = threadIdx.x; i < 512; i += blockDim.x)
        cur[i] = h[i] ? atomicAdd(&gcur[i], h[i]) : 0;
    __syncthreads();
    for (int e = e0 + threadIdx.x; e < e1; e += blockDim.x) {
        int d = dst[e];
        int pos = atomicAdd(&cur[d >> 8], 1);   // LDS atomic
        int2 v;
        v.x = ((d & 255) << 24) | src[e];       // src < 2^17, fits
        v.y = __float_as_int(ew[e]);
        packed[pos] = v;
    }
}

// One WG per bucket (256 nodes): count/scan/scatter in LDS, emit rptr/cnt/
// dinv + final CSR in the bucket's L2-hot window. No global atomics.
__global__ void bucket_build_kernel(const int2* __restrict__ packed,
                                    const int* __restrict__ bbase,
                                    int* __restrict__ rptr,
                                    int* __restrict__ cnt,
                                    float* __restrict__ dinv,
                                    int2* __restrict__ csr, int n) {
    __shared__ int cl[256];
    __shared__ int sc[256];
    __shared__ int cur[256];
    int b = blockIdx.x;
    int t = threadIdx.x;
    int node0 = b << 8;
    int nn = n - node0; if (nn > 256) nn = 256;
    int ebase = bbase[b];
    int m = bbase[b + 1] - ebase;
    cl[t] = 0;
    __syncthreads();
    for (int j = t; j < m; j += 256) {
        int local = ((unsigned)packed[ebase + j].x) >> 24;
        atomicAdd(&cl[local], 1);               // LDS atomic
    }
    __syncthreads();
    int c = cl[t];
    sc[t] = c;
    __syncthreads();
    for (int off = 1; off < 256; off <<= 1) {
        int u = (t >= off) ? sc[t - off] : 0;
        __syncthreads();
        sc[t] += u;
        __syncthreads();
    }
    int base = ebase + sc[t] - c;               // global CSR row start
    cur[t] = base;
    if (t < nn) {
        rptr[node0 + t] = base;
        cnt[node0 + t] = c;
    }
    __syncthreads();
    for (int j = t; j < m; j += 256) {
        int2 p = packed[ebase + j];
        int local = ((unsigned)p.x) >> 24;
        int pos = atomicAdd(&cur[local], 1);    // LDS atomic
        int2 v;
        v.x = p.x & 0x00FFFFFF;
        v.y = p.y;
        csr[pos] = v;
    }
    __syncthreads();
    if (t < nn) {
        float s = 0.0f;
        for (int j = base; j < base + c; ++j)
            s += __int_as_float(csr[j].y);
        dinv[node0 + t] = 1.0f / sqrtf(s + 1.0f);
    }
}

// GEMM via readlane broadcast (R13, proven).
template <bool RELU>
__global__ void __launch_bounds__(256, 4)
gemm_rl_kernel(const float* __restrict__ X, const float* W,
               const float* __restrict__ dinv, float* __restrict__ Ts,
               int n) {
    __shared__ float Wl[4096];
    {
        const float4* Wv = (const float4*)W;
        float4* Lv = (float4*)Wl;
        for (int i = threadIdx.x; i < 1024; i += 256) Lv[i] = Wv[i];
    }
    __syncthreads();
    int lane = threadIdx.x & 63;
    int wid  = (blockIdx.x * blockDim.x + threadIdx.x) >> 6;
    int nw   = (gridDim.x * blockDim.x) >> 6;
    int lrow = lane >> 4;
    int lcol = (lane & 15) * 4;
    for (int r0 = wid * 4; r0 + 4 <= n; r0 += nw * 4) {
        float4 xv = *(const float4*)&X[(size_t)(r0 + lrow) * 64 + lcol];
        if (RELU) {
            xv.x = fmaxf(xv.x, 0.f); xv.y = fmaxf(xv.y, 0.f);
            xv.z = fmaxf(xv.z, 0.f); xv.w = fmaxf(xv.w, 0.f);
        }
        float a0 = 0.f, a1 = 0.f, a2 = 0.f, a3 = 0.f;
#pragma unroll
        for (int k4 = 0; k4 < 16; ++k4) {
            float w0 = Wl[(4 * k4 + 0) * 64 + lane];
            float w1 = Wl[(4 * k4 + 1) * 64 + lane];
            float w2 = Wl[(4 * k4 + 2) * 64 + lane];
            float w3 = Wl[(4 * k4 + 3) * 64 + lane];
            a0 = fmaf(bcastf(xv.x, k4), w0, a0);
            a0 = fmaf(bcastf(xv.y, k4), w1, a0);
            a0 = fmaf(bcastf(xv.z, k4), w2, a0);
            a0 = fmaf(bcastf(xv.w, k4), w3, a0);
            a1 = fmaf(bcastf(xv.x, 16 + k4), w0, a1);
            a1 = fmaf(bcastf(xv.y, 16 + k4), w1, a1);
            a1 = fmaf(bcastf(xv.z, 16 + k4), w2, a1);
            a1 = fmaf(bcastf(xv.w, 16 + k4), w3, a1);
            a2 = fmaf(bcastf(xv.x, 32 + k4), w0, a2);
            a2 = fmaf(bcastf(xv.y, 32 + k4), w1, a2);
            a2 = fmaf(bcastf(xv.z, 32 + k4), w2, a2);
            a2 = fmaf(bcastf(xv.w, 32 + k4), w3, a2);
            a3 = fmaf(bcastf(xv.x, 48 + k4), w0, a3);
            a3 = fmaf(bcastf(xv.y, 48 + k4), w1, a3);
            a3 = fmaf(bcastf(xv.z, 48 + k4), w2, a3);
            a3 = fmaf(bcastf(xv.w, 48 + k4), w3, a3);
        }
        Ts[(size_t)(r0 + 0) * 64 + lane] = a0 * dinv[r0 + 0];
        Ts[(size_t)(r0 + 1) * 64 + lane] = a1 * dinv[r0 + 1];
        Ts[(size_t)(r0 + 2) * 64 + lane] = a2 * dinv[r0 + 2];
        Ts[(size_t)(r0 + 3) * 64 + lane] = a3 * dinv[r0 + 3];
    }
    if (wid == 0) {
        for (int r = (n & ~3); r < n; ++r) {
            const float4* xr = (const float4*)(X + (size_t)r * 64);
            float acc = 0.f;
#pragma unroll
            for (int k4 = 0; k4 < 16; ++k4) {
                float4 a = xr[k4];
                if (RELU) {
                    a.x = fmaxf(a.x, 0.f); a.y = fmaxf(a.y, 0.f);
                    a.z = fmaxf(a.z, 0.f); a.w = fmaxf(a.w, 0.f);
                }
                acc = fmaf(a.x, Wl[(4 * k4 + 0) * 64 + lane], acc);
                acc = fmaf(a.y, Wl[(4 * k4 + 1) * 64 + lane], acc);
                acc = fmaf(a.z, Wl[(4 * k4 + 2) * 64 + lane], acc);
                acc = fmaf(a.w, Wl[(4 * k4 + 3) * 64 + lane], acc);
            }
            Ts[(size_t)r * 64 + lane] = acc * dinv[r];
        }
    }
}

// Fused gather + next-layer gemm, READLANE epilogue (R15 proven form;
// R17 showed LDS-broadcast variant is 9us slower at VGPR=32).
__global__ void __launch_bounds__(256, 4)
fgather_kernel(const int2* __restrict__ csr,
               const int* __restrict__ rptr,
               const int* __restrict__ cnt,
               const float* __restrict__ dinv,
               const float* __restrict__ b,
               const float* __restrict__ Ts_in,
               const float* Wn,
               float* __restrict__ Ts_out, int n) {
    __shared__ float Wl[4096];
    {
        const float4* Wv = (const float4*)Wn;
        float4* Lv = (float4*)Wl;
        for (int i = threadIdx.x; i < 1024; i += 256) Lv[i] = Wv[i];
    }
    __syncthreads();
    int lane = threadIdx.x & 63;
    int r = (int)(((size_t)blockIdx.x * blockDim.x + threadIdx.x) >> 6);
    if (r >= n) return;
    int sub = lane >> 4;
    int cl  = lane & 15;
    int start = rptr[r];
    int m = cnt[r];
    float4 a0 = {0.f, 0.f, 0.f, 0.f};
    float4 a1 = {0.f, 0.f, 0.f, 0.f};
    float4 a2 = {0.f, 0.f, 0.f, 0.f};
    float4 a3 = {0.f, 0.f, 0.f, 0.f};
    int j = sub;
    for (; j + 12 < m; j += 16) {
        int2 e0 = csr[start + j];
        int2 e1 = csr[start + j + 4];
        int2 e2 = csr[start + j + 8];
        int2 e3 = csr[start + j + 12];
        float w0 = __int_as_float(e0.y);
        float w1 = __int_as_float(e1.y);
        float w2 = __int_as_float(e2.y);
        float w3 = __int_as_float(e3.y);
        float4 t0 = *(const float4*)&Ts_in[(size_t)e0.x * 64 + cl * 4];
        float4 t1 = *(const float4*)&Ts_in[(size_t)e1.x * 64 + cl * 4];
        float4 t2 = *(const float4*)&Ts_in[(size_t)e2.x * 64 + cl * 4];
        float4 t3 = *(const float4*)&Ts_in[(size_t)e3.x * 64 + cl * 4];
        a0.x = fmaf(t0.x, w0, a0.x); a0.y = fmaf(t0.y, w0, a0.y);
        a0.z = fmaf(t0.z, w0, a0.z); a0.w = fmaf(t0.w, w0, a0.w);
        a1.x = fmaf(t1.x, w1, a1.x); a1.y = fmaf(t1.y, w1, a1.y);
        a1.z = fmaf(t1.z, w1, a1.z); a1.w = fmaf(t1.w, w1, a1.w);
        a2.x = fmaf(t2.x, w2, a2.x); a2.y = fmaf(t2.y, w2, a2.y);
        a2.z = fmaf(t2.z, w2, a2.z); a2.w = fmaf(t2.w, w2, a2.w);
        a3.x = fmaf(t3.x, w3, a3.x); a3.y = fmaf(t3.y, w3, a3.y);
        a3.z = fmaf(t3.z, w3, a3.z); a3.w = fmaf(t3.w, w3, a3.w);
    }
    for (; j < m; j += 4) {
        int2 e0 = csr[start + j];
        float w0 = __int_as_float(e0.y);
        float4 t0 = *(const float4*)&Ts_in[(size_t)e0.x * 64 + cl * 4];
        a0.x = fmaf(t0.x, w0, a0.x); a0.y = fmaf(t0.y, w0, a0.y);
        a0.z = fmaf(t0.z, w0, a0.z); a0.w = fmaf(t0.w, w0, a0.w);
    }
    a0.x += a1.x + a2.x + a3.x;
    a0.y += a1.y + a2.y + a3.y;
    a0.z += a1.z + a2.z + a3.z;
    a0.w += a1.w + a2.w + a3.w;
#pragma unroll
    for (int off = 16; off < 64; off <<= 1) {
        a0.x += __shfl_xor(a0.x, off);
        a0.y += __shfl_xor(a0.y, off);
        a0.z += __shfl_xor(a0.z, off);
        a0.w += __shfl_xor(a0.w, off);
    }
    float dv = dinv[r];
    float4 ts = *(const float4*)&Ts_in[(size_t)r * 64 + cl * 4];
    float4 bb = *(const float4*)&b[cl * 4];
    float tx = fmaxf(fmaf(dv, a0.x + ts.x, bb.x), 0.f);
    float ty = fmaxf(fmaf(dv, a0.y + ts.y, bb.y), 0.f);
    float tz = fmaxf(fmaf(dv, a0.z + ts.z, bb.z), 0.f);
    float tw = fmaxf(fmaf(dv, a0.w + ts.w, bb.w), 0.f);
    // fused gemm, readlane broadcasts, 4 independent chains
    float c0 = 0.f, c1 = 0.f, c2 = 0.f, c3 = 0.f;
#pragma unroll
    for (int q = 0; q < 16; ++q) {
        c0 = fmaf(bcastf(tx, q), Wl[(4 * q + 0) * 64 + lane], c0);
        c1 = fmaf(bcastf(ty, q), Wl[(4 * q + 1) * 64 + lane], c1);
        c2 = fmaf(bcastf(tz, q), Wl[(4 * q + 2) * 64 + lane], c2);
        c3 = fmaf(bcastf(tw, q), Wl[(4 * q + 3) * 64 + lane], c3);
    }
    Ts_out[(size_t)r * 64 + lane] = ((c0 + c1) + (c2 + c3)) * dv;
}

// Final layer: gather + readout MLP fused; readlane epilogue; lane0 writes
// per-node scalar svbuf[r] (NO atomics -- sorted batch => convoy, R16).
__global__ void __launch_bounds__(256, 4)
rgather_kernel(const int2* __restrict__ csr,
               const int* __restrict__ rptr,
               const int* __restrict__ cnt,
               const float* __restrict__ dinv,
               const float* __restrict__ b,
               const float* __restrict__ Ts,
               const float* Wr0, const float* br0,
               const float* Wr1, const float* br1,
               float* __restrict__ svbuf, int n) {
    __shared__ float Wl[64 * 32];
    __shared__ float w1s[32];
    __shared__ float b0s[32];
    {
        const float4* Wv = (const float4*)Wr0;
        float4* Lv = (float4*)Wl;
        for (int i = threadIdx.x; i < 512; i += 256) Lv[i] = Wv[i];
        if (threadIdx.x < 32) {
            w1s[threadIdx.x] = Wr1[threadIdx.x];
            b0s[threadIdx.x] = br0[threadIdx.x];
        }
    }
    __syncthreads();
    int lane = threadIdx.x & 63;
    int r = (int)(((size_t)blockIdx.x * blockDim.x + threadIdx.x) >> 6);
    if (r >= n) return;
    int sub = lane >> 4;
    int cl  = lane & 15;
    int start = rptr[r];
    int m = cnt[r];
    float4 a0 = {0.f, 0.f, 0.f, 0.f};
    float4 a1 = {0.f, 0.f, 0.f, 0.f};
    float4 a2 = {0.f, 0.f, 0.f, 0.f};
    float4 a3 = {0.f, 0.f, 0.f, 0.f};
    int j = sub;
    for (; j + 12 < m; j += 16) {
        int2 e0 = csr[start + j];
        int2 e1 = csr[start + j + 4];
        int2 e2 = csr[start + j + 8];
        int2 e3 = csr[start + j + 12];
        float w0 = __int_as_float(e0.y);
        float w1 = __int_as_float(e1.y);
        float w2 = __int_as_float(e2.y);
        float w3 = __int_as_float(e3.y);
        float4 t0 = *(const float4*)&Ts[(size_t)e0.x * 64 + cl * 4];
        float4 t1 = *(const float4*)&Ts[(size_t)e1.x * 64 + cl * 4];
        float4 t2 = *(const float4*)&Ts[(size_t)e2.x * 64 + cl * 4];
        float4 t3 = *(const float4*)&Ts[(size_t)e3.x * 64 + cl * 4];
        a0.x = fmaf(t0.x, w0, a0.x); a0.y = fmaf(t0.y, w0, a0.y);
        a0.z = fmaf(t0.z, w0, a0.z); a0.w = fmaf(t0.w, w0, a0.w);
        a1.x = fmaf(t1.x, w1, a1.x); a1.y = fmaf(t1.y, w1, a1.y);
        a1.z = fmaf(t1.z, w1, a1.z); a1.w = fmaf(t1.w, w1, a1.w);
        a2.x = fmaf(t2.x, w2, a2.x); a2.y = fmaf(t2.y, w2, a2.y);
        a2.z = fmaf(t2.z, w2, a2.z); a2.w = fmaf(t2.w, w2, a2.w);
        a3.x = fmaf(t3.x, w3, a3.x); a3.y = fmaf(t3.y, w3, a3.y);
        a3.z = fmaf(t3.z, w3, a3.z); a3.w = fmaf(t3.w, w3, a3.w);
    }
    for (; j < m; j += 4) {
        int2 e0 = csr[start + j];
        float w0 = __int_as_float(e0.y);
        float4 t0 = *(const float4*)&Ts[(size_t)e0.x * 64 + cl * 4];
        a0.x = fmaf(t0.x, w0, a0.x); a0.y = fmaf(t0.y, w0, a0.y);
        a0.z = fmaf(t0.z, w0, a0.z); a0.w = fmaf(t0.w, w0, a0.w);
    }
    a0.x += a1.x + a2.x + a3.x;
    a0.y += a1.y + a2.y + a3.y;
    a0.z += a1.z + a2.z + a3.z;
    a0.w += a1.w + a2.w + a3.w;
#pragma unroll
    for (int off = 16; off < 64; off <<= 1) {
        a0.x += __shfl_xor(a0.x, off);
        a0.y += __shfl_xor(a0.y, off);
        a0.z += __shfl_xor(a0.z, off);
        a0.w += __shfl_xor(a0.w, off);
    }
    float dv = dinv[r];
    float4 ts = *(const float4*)&Ts[(size_t)r * 64 + cl * 4];
    float4 bb = *(const float4*)&b[cl * 4];
    float tx = fmaf(dv, a0.x + ts.x, bb.x);   // A row (no relu, last layer)
    float ty = fmaf(dv, a0.y + ts.y, bb.y);
    float tz = fmaf(dv, a0.z + ts.z, bb.z);
    float tw = fmaf(dv, a0.w + ts.w, bb.w);
    int hj = lane & 31;
    float c0 = 0.f, c1 = 0.f, c2 = 0.f, c3 = 0.f;
#pragma unroll
    for (int q = 0; q < 16; ++q) {
        c0 = fmaf(bcastf(tx, q), Wl[(4 * q + 0) * 32 + hj], c0);
        c1 = fmaf(bcastf(ty, q), Wl[(4 * q + 1) * 32 + hj], c1);
        c2 = fmaf(bcastf(tz, q), Wl[(4 * q + 2) * 32 + hj], c2);
        c3 = fmaf(bcastf(tw, q), Wl[(4 * q + 3) * 32 + hj], c3);
    }
    float h = fmaxf(((c0 + c1) + (c2 + c3)) + b0s[hj], 0.f);
    float p = h * w1s[hj];
#pragma unroll
    for (int off = 1; off < 32; off <<= 1) p += __shfl_xor(p, off);
    if (lane == 0) svbuf[r] = p + br1[0];
}

// Wave-segmented reduce of per-node scalars (batch sorted): heads atomically
// add per-run partials (~2 atomics/wave, no same-address convoy).
__global__ void segpool_kernel(const float* __restrict__ svbuf,
                               const int* __restrict__ batch,
                               float* __restrict__ gsum,
                               float* __restrict__ gcnt, int n) {
    int r = blockIdx.x * blockDim.x + threadIdx.x;
    int lane = threadIdx.x & 63;
    float sv = 0.0f;
    int g = -1;
    if (r < n) { sv = svbuf[r]; g = batch[r]; }
    float c = (r < n) ? 1.0f : 0.0f;
#pragma unroll
    for (int off = 1; off < 64; off <<= 1) {
        int   og = __shfl_down(g, off);
        float ov = __shfl_down(sv, off);
        float oc = __shfl_down(c, off);
        if ((lane + off) < 64 && og == g) { sv += ov; c += oc; }
    }
    int gprev = __shfl_up(g, 1);
    bool head = (lane == 0) || (gprev != g);
    if (head && g >= 0) {
        atomicAdd(&gsum[g], sv);
        atomicAdd(&gcnt[g], c);
    }
}

__global__ void pool_fin_kernel(const float* __restrict__ gsum,
                                const float* __restrict__ gcnt,
                                float* __restrict__ out, int ng) {
    int g = blockIdx.x * blockDim.x + threadIdx.x;
    if (g < ng) out[g] = gsum[g] / fmaxf(gcnt[g], 1.0f);
}

extern "C" void kernel_launch(void* const* d_in, const int* in_sizes, int n_in,
                              void* d_out, int out_size, void* d_ws, size_t ws_size,
                              hipStream_t stream) {
    const float* x    = (const float*)d_in[0];
    const int*   ei   = (const int*)d_in[1];
    const float* ew   = (const float*)d_in[2];
    const int*   batch= (const int*)d_in[3];
    const float* W0   = (const float*)d_in[4];
    const float* b0   = (const float*)d_in[5];
    const float* W1   = (const float*)d_in[6];
    const float* b1   = (const float*)d_in[7];
    const float* W2   = (const float*)d_in[8];
    const float* b2   = (const float*)d_in[9];
    const float* Wr0  = (const float*)d_in[10];
    const float* br0  = (const float*)d_in[11];
    const float* Wr1  = (const float*)d_in[12];
    const float* br1  = (const float*)d_in[13];
    float* out = (float*)d_out;

    int n  = in_sizes[0] / 64;   // 100000
    int ne = in_sizes[1] / 2;    // 1600000
    int ng = out_size;           // 256
    const int* srcv = ei;
    const int* dstv = ei + ne;
    int nbk = (n + 255) >> 8;    // 391

    char* ws = (char*)d_ws;
    size_t off = 0;
    auto alloc = [&](size_t bytes) {
        void* p = ws + off;
        off += (bytes + 255) & ~(size_t)255;
        return p;
    };
    float* Ts     = (float*)alloc((size_t)n * 64 * sizeof(float));
    float* A      = (float*)alloc((size_t)n * 64 * sizeof(float));
    float* dinv   = (float*)alloc((size_t)n * sizeof(float));
    float* svbuf  = (float*)alloc((size_t)n * sizeof(float));
    int*   cnt    = (int*)alloc((size_t)n * sizeof(int));
    int*   rptr   = (int*)alloc((size_t)n * sizeof(int));
    int*   bcnt   = (int*)alloc(520 * sizeof(int));
    int*   bbase  = (int*)alloc(520 * sizeof(int));
    int*   gcur   = (int*)alloc(520 * sizeof(int));
    int2*  csr    = (int2*)alloc((size_t)ne * sizeof(int2));
    float* gsum   = (float*)alloc((size_t)ng * sizeof(float));
    float* gcnt   = (float*)alloc((size_t)ng * sizeof(float));
    // packed aliases Ts: consumed by bucket_build before first gemm writes Ts.
    int2*  packed = (int2*)Ts;
    (void)ws_size;

    hipMemsetAsync(bcnt, 0, 520 * sizeof(int), stream);
    hipMemsetAsync(gsum, 0, (size_t)ng * sizeof(float), stream);
    hipMemsetAsync(gcnt, 0, (size_t)ng * sizeof(float), stream);

    hist_kernel<<<1024, 256, 0, stream>>>(dstv, bcnt, ne);
    bscan_kernel<<<1, 512, 0, stream>>>(bcnt, bbase, gcur, nbk, ne);
    scatterB_kernel<<<256, 256, 0, stream>>>(srcv, dstv, ew, gcur, packed, ne);
    bucket_build_kernel<<<nbk, 256, 0, stream>>>(packed, bbase, rptr, cnt,
                                                 dinv, csr, n);

    const int gemm_blocks = 2048;
    unsigned gat_blocks = (unsigned)(((size_t)n * 64 + 255) / 256);

    // gemm0: Ts = x@W0*dinv
    gemm_rl_kernel<false><<<gemm_blocks, 256, 0, stream>>>(x, W0, dinv, Ts, n);
    // layer1: A-buf <- relu(gather(Ts)+b0) @ W1 * dinv
    fgather_kernel<<<gat_blocks, 256, 0, stream>>>(csr, rptr, cnt, dinv, b0,
                                                   Ts, W1, A, n);
    // layer2: Ts <- relu(gather(A-buf)+b1) @ W2 * dinv
    fgather_kernel<<<gat_blocks, 256, 0, stream>>>(csr, rptr, cnt, dinv, b1,
                                                   A, W2, Ts, n);
    // layer3 + readout: svbuf[r] = MLP(gather(Ts)+b2)
    rgather_kernel<<<gat_blocks, 256, 0, stream>>>(csr, rptr, cnt, dinv, b2,
                                                   Ts, Wr0, br0, Wr1, br1,
                                                   svbuf, n);
    segpool_kernel<<<(n + 255) / 256, 256, 0, stream>>>(svbuf, batch,
                                                        gsum, gcnt, n);
    pool_fin_kernel<<<(ng + 255) / 256, 256, 0, stream>>>(gsum, gcnt, out, ng);
}